// Round 1
// baseline (202.800 us; speedup 1.0000x reference)
//
#include <hip/hip_runtime.h>
#include <hip/hip_bf16.h>

#define NNODES 8192
#define EMB    1024
#define HID    256
#define MAXDEG 128
#define ALPHA  0.2f

// ---------------------------------------------------------------------------
// Kernel 1: one block per row of adj. Computes rowsum -> dinv = rsqrt(sum),
// and extracts nonzero (col, val) pairs into cols/vals (sparse CSR-ish with
// fixed MAXDEG stride). adj has ~2 nonzeros/row (prefix tree), so MAXDEG=128
// is very safe; guarded anyway.
// ---------------------------------------------------------------------------
__global__ __launch_bounds__(256) void extract_kernel(
    const float* __restrict__ adj, float* __restrict__ dinv,
    int* __restrict__ nnz, int* __restrict__ cols, float* __restrict__ vals) {
  int row = blockIdx.x;
  const float4* arow = (const float4*)(adj + (size_t)row * NNODES);
  __shared__ int s_cnt;
  __shared__ float s_part[4];
  if (threadIdx.x == 0) s_cnt = 0;
  __syncthreads();

  float sum = 0.f;
  int base = row * MAXDEG;
  for (int c4 = threadIdx.x; c4 < NNODES / 4; c4 += 256) {
    float4 v = arow[c4];
    sum += v.x + v.y + v.z + v.w;
    if (v.x != 0.f) { int p = atomicAdd(&s_cnt, 1); if (p < MAXDEG) { cols[base + p] = c4 * 4 + 0; vals[base + p] = v.x; } }
    if (v.y != 0.f) { int p = atomicAdd(&s_cnt, 1); if (p < MAXDEG) { cols[base + p] = c4 * 4 + 1; vals[base + p] = v.y; } }
    if (v.z != 0.f) { int p = atomicAdd(&s_cnt, 1); if (p < MAXDEG) { cols[base + p] = c4 * 4 + 2; vals[base + p] = v.z; } }
    if (v.w != 0.f) { int p = atomicAdd(&s_cnt, 1); if (p < MAXDEG) { cols[base + p] = c4 * 4 + 3; vals[base + p] = v.w; } }
  }
  // wave (64-lane) reduce, then cross-wave via LDS
  for (int off = 32; off > 0; off >>= 1) sum += __shfl_down(sum, off, 64);
  int wave = threadIdx.x >> 6;
  if ((threadIdx.x & 63) == 0) s_part[wave] = sum;
  __syncthreads();
  if (threadIdx.x == 0) {
    float tot = s_part[0] + s_part[1] + s_part[2] + s_part[3];
    dinv[row] = rsqrtf(tot);
    int c = s_cnt;
    nnz[row] = (c > MAXDEG) ? MAXDEG : c;
  }
}

// ---------------------------------------------------------------------------
// Kernel 2: h0 = relu(X @ W + b).  M=8192, K=1024, N=256, f32 (no fp32 MFMA
// on CDNA4 -> vector FMA). 128x64 tile, BK=16, 256 threads, 8x4 micro-tile.
// ---------------------------------------------------------------------------
#define BM 128
#define BN 64
#define BK 16

__global__ __launch_bounds__(256) void gemm_relu_kernel(
    const float* __restrict__ X, const float* __restrict__ W,
    const float* __restrict__ bias, float* __restrict__ h0) {
  __shared__ float As[BK][BM];   // transposed A tile
  __shared__ float Bs[BK][BN];

  int m0 = blockIdx.x * BM;
  int n0 = blockIdx.y * BN;
  int tid = threadIdx.x;
  int tm = tid >> 4;     // 0..15 -> 8 rows each
  int tn = tid & 15;     // 0..15 -> 4 cols each

  int ar  = tid >> 2;    // 0..63 (row within half-tile)
  int ac4 = tid & 3;     // 0..3  (k-offset/4)
  int bk  = tid >> 4;    // 0..15 (k row of B tile)
  int bc4 = tid & 15;    // 0..15 (col/4)

  float acc[8][4] = {{0.f}};

  for (int k0 = 0; k0 < EMB; k0 += BK) {
    float4 a0 = *(const float4*)&X[(size_t)(m0 + ar) * EMB + k0 + ac4 * 4];
    float4 a1 = *(const float4*)&X[(size_t)(m0 + 64 + ar) * EMB + k0 + ac4 * 4];
    float4 bv = *(const float4*)&W[(size_t)(k0 + bk) * HID + n0 + bc4 * 4];

    __syncthreads();   // previous iteration's compute done before overwrite
    As[ac4 * 4 + 0][ar] = a0.x; As[ac4 * 4 + 1][ar] = a0.y;
    As[ac4 * 4 + 2][ar] = a0.z; As[ac4 * 4 + 3][ar] = a0.w;
    As[ac4 * 4 + 0][64 + ar] = a1.x; As[ac4 * 4 + 1][64 + ar] = a1.y;
    As[ac4 * 4 + 2][64 + ar] = a1.z; As[ac4 * 4 + 3][64 + ar] = a1.w;
    *(float4*)&Bs[bk][bc4 * 4] = bv;
    __syncthreads();

#pragma unroll
    for (int kk = 0; kk < BK; kk++) {
      float a[8], bb[4];
      *(float4*)&a[0] = *(float4*)&As[kk][tm * 8];
      *(float4*)&a[4] = *(float4*)&As[kk][tm * 8 + 4];
      *(float4*)&bb[0] = *(float4*)&Bs[kk][tn * 4];
#pragma unroll
      for (int i = 0; i < 8; i++)
#pragma unroll
        for (int j = 0; j < 4; j++)
          acc[i][j] += a[i] * bb[j];
    }
  }

  float4 bv = *(const float4*)&bias[n0 + tn * 4];
#pragma unroll
  for (int i = 0; i < 8; i++) {
    int row = m0 + tm * 8 + i;
    float4 o;
    o.x = fmaxf(acc[i][0] + bv.x, 0.f);
    o.y = fmaxf(acc[i][1] + bv.y, 0.f);
    o.z = fmaxf(acc[i][2] + bv.z, 0.f);
    o.w = fmaxf(acc[i][3] + bv.w, 0.f);
    *(float4*)&h0[(size_t)row * HID + n0 + tn * 4] = o;
  }
}

// ---------------------------------------------------------------------------
// Kernel 3: one APPNP step: h_out[i,:] = 0.8*d_i*sum_j(val*d_j*h_in[j,:]) +
// 0.2*h0[i,:].  One wave (64 lanes) per row; lane handles 4 features (float4).
// ---------------------------------------------------------------------------
__global__ __launch_bounds__(256) void prop_kernel(
    const float* __restrict__ h_in, const float* __restrict__ h0,
    float* __restrict__ h_out, const float* __restrict__ dinv,
    const int* __restrict__ nnz, const int* __restrict__ cols,
    const float* __restrict__ vals) {
  int wave = threadIdx.x >> 6;
  int lane = threadIdx.x & 63;
  int row = blockIdx.x * 4 + wave;

  float di = dinv[row];
  int n = nnz[row];
  int base = row * MAXDEG;

  float4 acc = {0.f, 0.f, 0.f, 0.f};
  for (int k = 0; k < n; k++) {
    int j = cols[base + k];
    float w = vals[base + k] * dinv[j];
    float4 hv = *(const float4*)&h_in[(size_t)j * HID + lane * 4];
    acc.x += w * hv.x; acc.y += w * hv.y;
    acc.z += w * hv.z; acc.w += w * hv.w;
  }
  float s = (1.f - ALPHA) * di;
  float4 h0v = *(const float4*)&h0[(size_t)row * HID + lane * 4];
  float4 o;
  o.x = s * acc.x + ALPHA * h0v.x;
  o.y = s * acc.y + ALPHA * h0v.y;
  o.z = s * acc.z + ALPHA * h0v.z;
  o.w = s * acc.w + ALPHA * h0v.w;
  *(float4*)&h_out[(size_t)row * HID + lane * 4] = o;
}

// ---------------------------------------------------------------------------
extern "C" void kernel_launch(void* const* d_in, const int* in_sizes, int n_in,
                              void* d_out, int out_size, void* d_ws, size_t ws_size,
                              hipStream_t stream) {
  const float* nodes = (const float*)d_in[0];   // [8192,1024]
  const float* W     = (const float*)d_in[1];   // [1024,256]
  const float* bias  = (const float*)d_in[2];   // [256]
  const float* adj   = (const float*)d_in[3];   // [8192,8192]
  float* out = (float*)d_out;                   // [8192,256]

  char* ws = (char*)d_ws;
  float* h0   = (float*)(ws);                                   // 8 MB
  float* htmp = (float*)(ws + (size_t)8 * 1024 * 1024);         // 8 MB
  float* dinv = (float*)(ws + (size_t)16 * 1024 * 1024);        // 32 KB
  int*   nnz  = (int*)  (ws + (size_t)16 * 1024 * 1024 + 32 * 1024);
  int*   cols = (int*)  (ws + (size_t)16 * 1024 * 1024 + 64 * 1024);          // 4 MB
  float* vals = (float*)(ws + (size_t)16 * 1024 * 1024 + 64 * 1024
                            + (size_t)4 * 1024 * 1024);                        // 4 MB

  extract_kernel<<<NNODES, 256, 0, stream>>>(adj, dinv, nnz, cols, vals);
  gemm_relu_kernel<<<dim3(NNODES / BM, HID / BN), 256, 0, stream>>>(nodes, W, bias, h0);

  const float* src = h0;
  float* dsts[6] = {htmp, out, htmp, out, htmp, out};
  for (int it = 0; it < 6; it++) {
    prop_kernel<<<NNODES / 4, 256, 0, stream>>>(src, h0, dsts[it], dinv, nnz, cols, vals);
    src = dsts[it];
  }
}